// Round 1
// baseline (204.265 us; speedup 1.0000x reference)
//
#include <hip/hip_runtime.h>
#include <hip/hip_bf16.h>
#include <cstdint>

#define BDIM 256
constexpr int NB = 256;   // batch
constexpr int NT = 512;   // frames
constexpr int ND = 512;   // dim

typedef __attribute__((ext_vector_type(8))) short bf16x8;
typedef __attribute__((ext_vector_type(4))) float f32x4;
typedef __attribute__((ext_vector_type(4))) unsigned int u32x4;

__device__ __forceinline__ float wred_sum(float v){
#pragma unroll
  for (int m = 32; m > 0; m >>= 1) v += __shfl_xor(v, m, 64);
  return v;
}
__device__ __forceinline__ float wred_max(float v){
#pragma unroll
  for (int m = 32; m > 0; m >>= 1) v = fmaxf(v, __shfl_xor(v, m, 64));
  return v;
}
// f32 -> bf16 round-to-nearest-even
__device__ __forceinline__ unsigned short f2bf(float f){
  unsigned int u = __builtin_bit_cast(unsigned int, f);
  u = u + 0x7fffu + ((u >> 16) & 1u);
  return (unsigned short)(u >> 16);
}

// K0: sentence norms -> normalized bf16 rows + 1/norm
__global__ __launch_bounds__(BDIM) void k_sent(const float* __restrict__ s,
                                               unsigned short* __restrict__ sb,
                                               float* __restrict__ sinv){
  int row  = blockIdx.x * 4 + (threadIdx.x >> 6);
  int lane = threadIdx.x & 63;
  const float* sr = s + (size_t)row * ND;
  float x[8]; float ss = 0.f;
#pragma unroll
  for (int e = 0; e < 8; e++){ x[e] = sr[lane + e*64]; ss += x[e]*x[e]; }
  ss = wred_sum(ss);
  float inv = 1.0f / fmaxf(sqrtf(ss), 1e-8f);
#pragma unroll
  for (int e = 0; e < 8; e++) sb[(size_t)row*ND + lane + e*64] = f2bf(x[e]*inv);
  if (lane == 0) sinv[row] = inv;
}

// K1: per (b,t) video row: 1/norm, and full-f32 diagonal dot with sentence b.
// diag goes into the out1 region (overwritten later by k_argmax).
__global__ __launch_bounds__(BDIM) void k_vnorm(const float* __restrict__ v,
                                                const float* __restrict__ s,
                                                const float* __restrict__ sinv,
                                                float* __restrict__ vinv,
                                                float* __restrict__ diag){
  int row  = blockIdx.x * 4 + (threadIdx.x >> 6);   // b*512 + t
  int lane = threadIdx.x & 63;
  int b = row >> 9;
  const float* vr = v + (size_t)row * ND;
  const float* sr = s + (size_t)b * ND;
  float ss = 0.f, dt = 0.f;
#pragma unroll
  for (int e = 0; e < 8; e++){
    float x = vr[lane + e*64];
    float y = sr[lane + e*64];
    ss += x*x; dt += x*y;
  }
  ss = wred_sum(ss); dt = wred_sum(dt);
  if (lane == 0){
    float inv = 1.0f / fmaxf(sqrtf(ss), 1e-8f);
    vinv[row] = inv;
    diag[row] = dt * inv * sinv[b];
  }
}

// K2: per b: argmax over valid t of diag (first-index tie-break), copy frame row.
__global__ __launch_bounds__(BDIM) void k_argmax(const float* __restrict__ video,
                                                 const int* __restrict__ lens,
                                                 float* __restrict__ o1){
  int b = blockIdx.x;
  int tid = threadIdx.x;
  int len = lens[b];
  __shared__ float sv[BDIM];
  __shared__ int   si[BDIM];
  const float* diag = o1 + (size_t)b * NT;
  float v1 = (tid       < len) ? diag[tid]       : -__builtin_inff();
  float v2 = (tid + 256 < len) ? diag[tid + 256] : -__builtin_inff();
  float bv; int bi;
  if (v2 > v1){ bv = v2; bi = tid + 256; } else { bv = v1; bi = tid; }
  sv[tid] = bv; si[tid] = bi;
  __syncthreads();
  for (int sN = 128; sN > 0; sN >>= 1){
    if (tid < sN){
      float ov = sv[tid+sN]; int oi = si[tid+sN];
      if (ov > sv[tid] || (ov == sv[tid] && oi < si[tid])){ sv[tid] = ov; si[tid] = oi; }
    }
    __syncthreads();
  }
  int best = si[0];
  const float* src = video + ((size_t)b * NT + best) * ND;
  o1[(size_t)b * ND + tid]       = src[tid];
  o1[(size_t)b * ND + tid + 256] = src[tid + 256];
}

// K3: batched GEMM sim[b][j][t] = sum_d sn_bf16[j][d] * (v[b][t][d]*vinv[b][t])_bf16
// tile 128(j) x 128(t), BK=64, 4 waves 2x2, 16x16x32 bf16 MFMA,
// LDS XOR-swizzle (row&7)<<4 on 16B granules to kill stride-128B bank conflicts.
__global__ __launch_bounds__(BDIM) void k_gemm(const unsigned short* __restrict__ sb,
                                               const float* __restrict__ v,
                                               const float* __restrict__ vinv,
                                               float* __restrict__ out0){
  const int tid  = threadIdx.x;
  const int lane = tid & 63;
  const int w    = tid >> 6;
  const int bx   = blockIdx.x;
  const int b    = bx >> 3;
  const int tile = bx & 7;
  const int jt = (tile >> 2) * 128;
  const int tt = (tile & 3) * 128;

  __shared__ __align__(16) unsigned short As[128*64];
  __shared__ __align__(16) unsigned short Bs[128*64];

  int rowS[4], gS[4];
  float vs[4];
#pragma unroll
  for (int c = 0; c < 4; c++){
    int gl = c*256 + tid;
    rowS[c] = gl >> 3; gS[c] = gl & 7;
    vs[c] = vinv[b*NT + tt + rowS[c]];
  }

  f32x4 acc[4][4] = {};

  const size_t vbase = ((size_t)b * NT + tt) * ND;
  const size_t abase = (size_t)jt * ND;

  for (int k0 = 0; k0 < ND; k0 += 64){
    __syncthreads();
    // stage A (bf16 sentences, plain copy)
#pragma unroll
    for (int c = 0; c < 4; c++){
      int row = rowS[c], g = gS[c];
      u32x4 d = *reinterpret_cast<const u32x4*>(sb + abase + (size_t)row*ND + k0 + g*8);
      *reinterpret_cast<u32x4*>(reinterpret_cast<char*>(As) + row*128 + ((g ^ (row&7))<<4)) = d;
    }
    // stage B (f32 video -> scale by 1/norm -> bf16)
#pragma unroll
    for (int c = 0; c < 4; c++){
      int row = rowS[c], g = gS[c];
      const float* src = v + vbase + (size_t)row*ND + k0 + g*8;
      f32x4 x0 = *reinterpret_cast<const f32x4*>(src);
      f32x4 x1 = *reinterpret_cast<const f32x4*>(src + 4);
      float sc = vs[c];
      unsigned short h[8];
#pragma unroll
      for (int i = 0; i < 4; i++){ h[i] = f2bf(x0[i]*sc); h[4+i] = f2bf(x1[i]*sc); }
      u32x4 d;
      d[0] = h[0] | ((unsigned)h[1] << 16);
      d[1] = h[2] | ((unsigned)h[3] << 16);
      d[2] = h[4] | ((unsigned)h[5] << 16);
      d[3] = h[6] | ((unsigned)h[7] << 16);
      *reinterpret_cast<u32x4*>(reinterpret_cast<char*>(Bs) + row*128 + ((g ^ (row&7))<<4)) = d;
    }
    __syncthreads();
    // compute
#pragma unroll
    for (int ks = 0; ks < 2; ks++){
      bf16x8 af[4], bg[4];
#pragma unroll
      for (int f = 0; f < 4; f++){
        int row = ((w>>1)<<6) + f*16 + (lane&15);
        int gr  = ks*4 + (lane>>4);
        af[f] = *reinterpret_cast<const bf16x8*>(reinterpret_cast<const char*>(As) + row*128 + ((gr ^ (row&7))<<4));
      }
#pragma unroll
      for (int f = 0; f < 4; f++){
        int row = ((w&1)<<6) + f*16 + (lane&15);
        int gr  = ks*4 + (lane>>4);
        bg[f] = *reinterpret_cast<const bf16x8*>(reinterpret_cast<const char*>(Bs) + row*128 + ((gr ^ (row&7))<<4));
      }
#pragma unroll
      for (int fi = 0; fi < 4; fi++)
#pragma unroll
        for (int fj = 0; fj < 4; fj++)
          acc[fi][fj] = __builtin_amdgcn_mfma_f32_16x16x32_bf16(af[fi], bg[fj], acc[fi][fj], 0, 0, 0);
    }
  }

  const int wj = (w>>1)*64, wt = (w&1)*64;
#pragma unroll
  for (int fi = 0; fi < 4; fi++){
#pragma unroll
    for (int r = 0; r < 4; r++){
      int j = jt + wj + fi*16 + ((lane>>4)<<2) + r;
      float* orow = out0 + ((size_t)b*NB + j)*NT + tt + wt + (lane&15);
#pragma unroll
      for (int fj = 0; fj < 4; fj++)
        orow[fj*16] = acc[fi][fj][r];
    }
  }
}

// K4: in-place masked softmax over t (512 contiguous f32), one wave per row.
__global__ __launch_bounds__(BDIM) void k_softmax(float* __restrict__ out0,
                                                  const int* __restrict__ lens){
  int row  = blockIdx.x * 4 + (threadIdx.x >> 6);   // b*256 + j
  int lane = threadIdx.x & 63;
  int b = row >> 8;
  int len = lens[b];
  float* p = out0 + (size_t)row * NT;
  f32x4 x0 = *reinterpret_cast<const f32x4*>(p + lane*4);
  f32x4 x1 = *reinterpret_cast<const f32x4*>(p + 256 + lane*4);
  float mx = -__builtin_inff();
#pragma unroll
  for (int i = 0; i < 4; i++){
    if (lane*4 + i       < len) mx = fmaxf(mx, x0[i]);
    if (256 + lane*4 + i < len) mx = fmaxf(mx, x1[i]);
  }
  mx = wred_max(mx);
  float sum = 0.f;
  f32x4 e0, e1;
#pragma unroll
  for (int i = 0; i < 4; i++){
    e0[i] = (lane*4 + i       < len) ? __expf(x0[i] - mx) : 0.f;
    e1[i] = (256 + lane*4 + i < len) ? __expf(x1[i] - mx) : 0.f;
    sum += e0[i] + e1[i];
  }
  sum = wred_sum(sum);
  float inv = 1.0f / sum;
#pragma unroll
  for (int i = 0; i < 4; i++){ e0[i] *= inv; e1[i] *= inv; }
  *reinterpret_cast<f32x4*>(p + lane*4)       = e0;
  *reinterpret_cast<f32x4*>(p + 256 + lane*4) = e1;
}

extern "C" void kernel_launch(void* const* d_in, const int* in_sizes, int n_in,
                              void* d_out, int out_size, void* d_ws, size_t ws_size,
                              hipStream_t stream){
  const float* video = (const float*)d_in[0];
  const float* sent  = (const float*)d_in[1];
  const int*   lens  = (const int*)d_in[2];
  float* out0 = (float*)d_out;
  float* out1 = out0 + (size_t)NB*NB*NT;

  char* ws = (char*)d_ws;
  unsigned short* sb = (unsigned short*)ws;            // 256*512*2 = 262144 B
  float* sinv = (float*)(ws + 262144);                 // 1024 B
  float* vinv = (float*)(ws + 263168);                 // 131072*4 = 524288 B
  // total ws usage: ~0.75 MB

  k_sent   <<<NB/4,        BDIM, 0, stream>>>(sent, sb, sinv);
  k_vnorm  <<<NB*NT/4,     BDIM, 0, stream>>>(video, sent, sinv, vinv, out1);
  k_argmax <<<NB,          BDIM, 0, stream>>>(video, lens, out1);
  k_gemm   <<<NB*8,        BDIM, 0, stream>>>(sb, video, vinv, out0);
  k_softmax<<<NB*NB/4,     BDIM, 0, stream>>>(out0, lens);
}